// Round 3
// baseline (584.093 us; speedup 1.0000x reference)
//
#include <hip/hip_runtime.h>
#include <math.h>

// GraphQNetwork: 2-layer GAT (H=4 heads, C=64, concat=False/head-mean) + 3 FC + per-graph min.
// N=50000, E=400000, NG=64 (derived from in_sizes at launch).

__device__ __forceinline__ float gelu_f(float x){
    return 0.5f * x * (1.0f + erff(x * 0.70710678118654752f));
}

// order-preserving double <-> uint64 encode (for atomicMax-based segment max)
__device__ __forceinline__ unsigned long long enc_d(double v){
    unsigned long long u = (unsigned long long)__double_as_longlong(v);
    return (u >> 63) ? ~u : (u | 0x8000000000000000ULL);
}
__device__ __forceinline__ double dec_d(unsigned long long u){
    u = (u >> 63) ? (u & 0x7FFFFFFFFFFFFFFFULL) : ~u;
    return __longlong_as_double((long long)u);
}

// ---------------- edge stats (mean of modified edge_attr) + in-degree histogram ----------------
__global__ void k_edge_stats(const int* __restrict__ ei, const float* __restrict__ ea,
                             int E, double* __restrict__ dsum, int* __restrict__ deg){
    __shared__ double s0[256], s1[256], s2[256];
    int t = threadIdx.x;
    double a0 = 0, a1 = 0, a2 = 0;
    for (int e = blockIdx.x * blockDim.x + t; e < E; e += gridDim.x * blockDim.x){
        float e0 = ea[e*3+0], e1 = ea[e*3+1], e2 = ea[e*3+2];
        a0 += (double)e0;
        a1 += (double)e1;
        a2 += 1.0e6 / (double)e2;   // in-place edit: 1e6 / spectral_efficiency
        atomicAdd(&deg[ei[E + e]], 1);   // dst = edge_index[1]
    }
    s0[t] = a0; s1[t] = a1; s2[t] = a2;
    __syncthreads();
    for (int off = 128; off > 0; off >>= 1){
        if (t < off){ s0[t] += s0[t+off]; s1[t] += s1[t+off]; s2[t] += s2[t+off]; }
        __syncthreads();
    }
    if (t == 0){
        atomicAdd(&dsum[0], s0[0]);
        atomicAdd(&dsum[1], s1[0]);
        atomicAdd(&dsum[2], s2[0]);
    }
}

// ---------------- tiny parameter precompute ----------------
__global__ void k_params(const double* __restrict__ dsum, int E,
                         const float* __restrict__ convW, const float* __restrict__ attS,
                         const float* __restrict__ attD, const float* __restrict__ We,
                         const float* __restrict__ attE,
                         double* __restrict__ Mm, double* __restrict__ ael,
                         float* __restrict__ Wsrc, float* __restrict__ Wdst,
                         float* __restrict__ Wt){
    int t = threadIdx.x;
    if (t < 24){
        int l = t / 12, r = t % 12, j = r / 4, h = r % 4;
        double s = 0;
        for (int c = 0; c < 64; c++)
            s += (double)We[l*768 + j*256 + h*64 + c] * (double)attE[l*256 + h*64 + c];
        Mm[l*12 + j*4 + h] = s;
    }
    __syncthreads();
    if (t < 8){
        int l = t / 4, h = t % 4;
        double s = 0;
        for (int j = 0; j < 3; j++)
            s += (dsum[j] / (double)E) * Mm[l*12 + j*4 + h];
        ael[l*4 + h] = s;
    }
    for (int idx = t; idx < 512; idx += 256){
        int l = idx >> 8, k = (idx >> 2) & 63, h = idx & 3;
        float ss = 0.f, sd = 0.f;
        for (int c = 0; c < 64; c++){
            float wv = convW[l*16384 + k*256 + h*64 + c];
            ss += wv * attS[l*256 + h*64 + c];
            sd += wv * attD[l*256 + h*64 + c];
        }
        Wsrc[idx] = ss; Wdst[idx] = sd;
    }
    for (int idx = t; idx < 32768; idx += 256){
        int l = idx >> 14, p = (idx >> 6) & 255, c = idx & 63;
        int h = p >> 6, k = p & 63;
        Wt[idx] = 0.25f * convW[l*16384 + k*256 + h*64 + c];
    }
}

// ---------------- CSR build ----------------
__global__ void k_chunk_sum(const int* __restrict__ deg, int n, int* __restrict__ csum){
    __shared__ int s[256];
    int t = threadIdx.x, base = blockIdx.x * 1024;
    int v = 0;
    for (int j = t; j < 1024; j += 256){ int i = base + j; if (i < n) v += deg[i]; }
    s[t] = v; __syncthreads();
    for (int off = 128; off > 0; off >>= 1){ if (t < off) s[t] += s[t+off]; __syncthreads(); }
    if (t == 0) csum[blockIdx.x] = s[0];
}

__global__ void k_chunk_scan(const int* __restrict__ csum, int nchunks,
                             int* __restrict__ coff, int* __restrict__ rp_end){
    if (threadIdx.x == 0){
        int run = 0;
        for (int i = 0; i < nchunks; i++){ coff[i] = run; run += csum[i]; }
        *rp_end = run;
    }
}

__global__ void __launch_bounds__(1024) k_row_ptr(const int* __restrict__ deg, int n,
                          const int* __restrict__ coff,
                          int* __restrict__ row_ptr, int* __restrict__ cursor){
    __shared__ int s[1024];
    int t = threadIdx.x, i = blockIdx.x * 1024 + t;
    int v = (i < n) ? deg[i] : 0;
    s[t] = v; __syncthreads();
    for (int off = 1; off < 1024; off <<= 1){
        int x = (t >= off) ? s[t-off] : 0;
        __syncthreads();
        s[t] += x;
        __syncthreads();
    }
    if (i < n){
        int e = coff[blockIdx.x] + s[t] - v;   // exclusive
        row_ptr[i] = e; cursor[i] = e;
    }
}

__global__ void k_scatter(const int* __restrict__ ei, int E, int* __restrict__ cursor,
                          int* __restrict__ col_src, int* __restrict__ col_dst,
                          int* __restrict__ col_eid){
    for (int e = blockIdx.x * blockDim.x + threadIdx.x; e < E; e += gridDim.x * blockDim.x){
        int d = ei[E + e];
        int pos = atomicAdd(&cursor[d], 1);
        col_src[pos] = ei[e];
        col_dst[pos] = d;
        col_eid[pos] = e;
    }
}

// ---------------- input projection: h = gelu(x @ linW + linb), D_IN=15 ----------------
__global__ void k_lin_in(const float* __restrict__ x, const float* __restrict__ W,
                         const float* __restrict__ b, float* __restrict__ h, int n){
    int t = threadIdx.x;
    int row = blockIdx.x * 4 + (t >> 6);
    int c = t & 63;
    if (row >= n) return;
    float acc = b[c];
    #pragma unroll
    for (int j = 0; j < 15; j++) acc += x[row*15 + j] * W[j*64 + c];
    h[row*64 + c] = gelu_f(acc);
}

// ---------------- attention coefficients: a_src/a_dst = h @ Wsrc/Wdst ([64,4]) ----------------
__global__ void k_attcoef(const float* __restrict__ h, const float* __restrict__ Wsrc,
                          const float* __restrict__ Wdst, float* __restrict__ asrc,
                          float* __restrict__ adst, int n){
    int i = blockIdx.x * blockDim.x + threadIdx.x;
    if (i >= n) return;
    const float4* h4 = (const float4*)(h + (size_t)i * 64);
    const float4* ws4 = (const float4*)Wsrc;
    const float4* wd4 = (const float4*)Wdst;
    float4 s = {0,0,0,0}, d = {0,0,0,0};
    #pragma unroll
    for (int k4 = 0; k4 < 16; k4++){
        float4 hv = h4[k4];
        float4 w;
        w = ws4[k4*4+0]; s.x += hv.x*w.x; s.y += hv.x*w.y; s.z += hv.x*w.z; s.w += hv.x*w.w;
        w = ws4[k4*4+1]; s.x += hv.y*w.x; s.y += hv.y*w.y; s.z += hv.y*w.z; s.w += hv.y*w.w;
        w = ws4[k4*4+2]; s.x += hv.z*w.x; s.y += hv.z*w.y; s.z += hv.z*w.z; s.w += hv.z*w.w;
        w = ws4[k4*4+3]; s.x += hv.w*w.x; s.y += hv.w*w.y; s.z += hv.w*w.z; s.w += hv.w*w.w;
        w = wd4[k4*4+0]; d.x += hv.x*w.x; d.y += hv.x*w.y; d.z += hv.x*w.z; d.w += hv.x*w.w;
        w = wd4[k4*4+1]; d.x += hv.y*w.x; d.y += hv.y*w.y; d.z += hv.y*w.z; d.w += hv.y*w.w;
        w = wd4[k4*4+2]; d.x += hv.z*w.x; d.y += hv.z*w.y; d.z += hv.z*w.z; d.w += hv.z*w.w;
        w = wd4[k4*4+3]; d.x += hv.w*w.x; d.y += hv.w*w.y; d.z += hv.w*w.z; d.w += hv.w*w.w;
    }
    ((float4*)asrc)[i] = s;
    ((float4*)adst)[i] = d;
}

// ---------------- self-loop logit + init segment max ----------------
__global__ void k_self_m(const float* __restrict__ asrc, const float* __restrict__ adst,
                         const double* __restrict__ ael, double4* __restrict__ dself,
                         unsigned long long* __restrict__ menc, int n){
    int i = blockIdx.x * blockDim.x + threadIdx.x;
    if (i >= n) return;
    float4 av = ((const float4*)asrc)[i];
    float4 bv = ((const float4*)adst)[i];
    double a[4] = {av.x, av.y, av.z, av.w};
    double b[4] = {bv.x, bv.y, bv.z, bv.w};
    double vv[4];
    #pragma unroll
    for (int h = 0; h < 4; h++){
        double x = a[h] + b[h] + ael[h];
        if (x < 0.0) x *= 0.2;
        vv[h] = x;
        menc[i*4 + h] = enc_d(x);
    }
    double4 o; o.x = vv[0]; o.y = vv[1]; o.z = vv[2]; o.w = vv[3];
    dself[i] = o;
}

// ---------------- per-edge logits (f64) + segment max via atomicMax (exact) ----------------
__global__ void k_edge_dd(const int* __restrict__ col_src, const int* __restrict__ col_dst,
                          const int* __restrict__ col_eid, const float* __restrict__ ea,
                          const float* __restrict__ asrc, const float* __restrict__ adst,
                          const double* __restrict__ Mm, double4* __restrict__ dd,
                          unsigned long long* __restrict__ menc, int E){
    int p = blockIdx.x * blockDim.x + threadIdx.x;
    if (p >= E) return;
    int e = col_eid[p];
    int s = col_src[p];
    int d = col_dst[p];
    double e0 = (double)ea[e*3+0];
    double e1 = (double)ea[e*3+1];
    double e2m = 1.0e6 / (double)ea[e*3+2];
    float4 av = ((const float4*)asrc)[s];
    float4 bv = ((const float4*)adst)[d];
    double as_[4] = {av.x, av.y, av.z, av.w};
    double ad_[4] = {bv.x, bv.y, bv.z, bv.w};
    double vv[4];
    #pragma unroll
    for (int h = 0; h < 4; h++){
        double aeh = e0*Mm[h] + e1*Mm[4+h] + e2m*Mm[8+h];
        double x = as_[h] + ad_[h] + aeh;
        if (x < 0.0) x *= 0.2;                 // leaky_relu 0.2
        vv[h] = x;
        atomicMax(&menc[d*4 + h], enc_d(x));
    }
    double4 o; o.x = vv[0]; o.y = vv[1]; o.z = vv[2]; o.w = vv[3];
    dd[p] = o;
}

// ---------------- per-edge p = exp(dd - m[dst]) ----------------
__global__ void k_edge_p(const double4* __restrict__ dd, const int* __restrict__ col_dst,
                         const unsigned long long* __restrict__ menc,
                         float4* __restrict__ pbuf, int E){
    int p = blockIdx.x * blockDim.x + threadIdx.x;
    if (p >= E) return;
    int d = col_dst[p];
    double4 v = dd[p];
    float4 o;
    o.x = expf((float)(v.x - dec_d(menc[d*4+0])));
    o.y = expf((float)(v.y - dec_d(menc[d*4+1])));
    o.z = expf((float)(v.z - dec_d(menc[d*4+2])));
    o.w = expf((float)(v.w - dec_d(menc[d*4+3])));
    pbuf[p] = o;
}

// ---------------- aggregation: wave per node, lane = channel; p precomputed ----------------
__global__ void k_aggregate2(const float* __restrict__ hin, const double4* __restrict__ dself,
                             const unsigned long long* __restrict__ menc,
                             const int* __restrict__ row_ptr, const int* __restrict__ col_src,
                             const float4* __restrict__ pbuf, float* __restrict__ agg, int n){
    int w = threadIdx.x >> 6, lane = threadIdx.x & 63;
    int i = blockIdx.x * 4 + w;
    if (i >= n) return;

    double4 ds = dself[i];
    float ps[4];
    ps[0] = expf((float)(ds.x - dec_d(menc[i*4+0])));
    ps[1] = expf((float)(ds.y - dec_d(menc[i*4+1])));
    ps[2] = expf((float)(ds.z - dec_d(menc[i*4+2])));
    ps[3] = expf((float)(ds.w - dec_d(menc[i*4+3])));

    float hself = hin[(size_t)i*64 + lane];
    float ssum[4], acc[4];
    #pragma unroll
    for (int h = 0; h < 4; h++){ ssum[h] = ps[h]; acc[h] = ps[h] * hself; }

    int r0 = row_ptr[i], r1 = row_ptr[i+1];
    for (int e = r0; e < r1; e++){
        int s = col_src[e];
        float hv = hin[(size_t)s*64 + lane];
        float4 p4 = pbuf[e];
        acc[0] += p4.x * hv; ssum[0] += p4.x;
        acc[1] += p4.y * hv; ssum[1] += p4.y;
        acc[2] += p4.z * hv; ssum[2] += p4.z;
        acc[3] += p4.w * hv; ssum[3] += p4.w;
    }
    #pragma unroll
    for (int h = 0; h < 4; h++){
        float inv = 1.0f / (ssum[h] + 1e-16f);
        agg[(size_t)i*256 + h*64 + lane] = acc[h] * inv;
    }
}

// ---------------- tiled GEMM: out[n,64] = act(A[n,K] @ B[K,64] + bias (+res)) ----------------
template<int K, bool RES, bool GEL>
__global__ void __launch_bounds__(256) k_gemm(const float* __restrict__ A, const float* __restrict__ B,
                      const float* __restrict__ bias, const float* __restrict__ res,
                      float* __restrict__ out, int n){
    __shared__ float Bs[K * 64];
    int t = threadIdx.x;
    for (int idx = t; idx < K*64; idx += 256) Bs[idx] = B[idx];
    __syncthreads();

    int row0 = blockIdx.x * 64;
    int tr = t >> 4, tc = t & 15;
    int r = row0 + tr*4;
    int c = tc*4;
    float acc[4][4] = {};

    int rr[4];
    #pragma unroll
    for (int i = 0; i < 4; i++){ int q = r + i; rr[i] = (q < n) ? q : (n - 1); }

    const float4* A4 = (const float4*)A;
    for (int k4 = 0; k4 < K/4; k4++){
        float4 b0 = *(const float4*)&Bs[(k4*4+0)*64 + c];
        float4 b1 = *(const float4*)&Bs[(k4*4+1)*64 + c];
        float4 b2 = *(const float4*)&Bs[(k4*4+2)*64 + c];
        float4 b3 = *(const float4*)&Bs[(k4*4+3)*64 + c];
        #pragma unroll
        for (int i = 0; i < 4; i++){
            float4 a = A4[(size_t)rr[i]*(K/4) + k4];
            acc[i][0] += a.x*b0.x + a.y*b1.x + a.z*b2.x + a.w*b3.x;
            acc[i][1] += a.x*b0.y + a.y*b1.y + a.z*b2.y + a.w*b3.y;
            acc[i][2] += a.x*b0.z + a.y*b1.z + a.z*b2.z + a.w*b3.z;
            acc[i][3] += a.x*b0.w + a.y*b1.w + a.z*b2.w + a.w*b3.w;
        }
    }

    float4 bb = *(const float4*)&bias[c];
    #pragma unroll
    for (int i = 0; i < 4; i++){
        int q = r + i;
        if (q < n){
            float4 v;
            v.x = acc[i][0] + bb.x; v.y = acc[i][1] + bb.y;
            v.z = acc[i][2] + bb.z; v.w = acc[i][3] + bb.w;
            if (RES){
                float4 rv = *(const float4*)&res[(size_t)q*64 + c];
                v.x += rv.x; v.y += rv.y; v.z += rv.z; v.w += rv.w;
            }
            if (GEL){
                v.x = gelu_f(v.x); v.y = gelu_f(v.y);
                v.z = gelu_f(v.z); v.w = gelu_f(v.w);
            }
            *(float4*)&out[(size_t)q*64 + c] = v;
        }
    }
}

// ---------------- fc3 + per-graph min (hierarchical: wave -> LDS -> global) ----------------
__global__ void k_fc3(const float* __restrict__ h, const float* __restrict__ W,
                      const float* __restrict__ b, const int* __restrict__ batch,
                      unsigned int* __restrict__ qenc, int n){
    __shared__ unsigned smin[64];
    int t = threadIdx.x;
    if (t < 64) smin[t] = 0xFFFFFFFFu;
    __syncthreads();

    int i = blockIdx.x * blockDim.x + t;
    unsigned u = 0xFFFFFFFFu;
    int g = -1;
    if (i < n){
        float q = b[0];
        const float4* h4 = (const float4*)(h + (size_t)i*64);
        const float4* w4 = (const float4*)W;
        #pragma unroll
        for (int k = 0; k < 16; k++){
            float4 hv = h4[k], wv = w4[k];
            q += hv.x*wv.x + hv.y*wv.y + hv.z*wv.z + hv.w*wv.w;
        }
        unsigned enc = __float_as_uint(q);
        u = (enc & 0x80000000u) ? ~enc : (enc | 0x80000000u);   // order-preserving encode
        g = batch[i];
    }
    int g0 = __shfl(g, 0);
    bool uni = __all(g == g0);
    if (uni){
        #pragma unroll
        for (int off = 32; off > 0; off >>= 1){
            unsigned o = __shfl_xor(u, off);
            u = (o < u) ? o : u;
        }
        if ((t & 63) == 0 && g0 >= 0) atomicMin(&smin[g0], u);
    } else if (i < n){
        atomicMin(&smin[g], u);
    }
    __syncthreads();
    if (t < 64 && smin[t] != 0xFFFFFFFFu) atomicMin(&qenc[t], smin[t]);
}

__global__ void k_qout(const unsigned int* __restrict__ qenc, float* __restrict__ out){
    int g = threadIdx.x;
    unsigned u = qenc[g];
    u = (u & 0x80000000u) ? (u & 0x7FFFFFFFu) : ~u;   // decode
    out[g] = __uint_as_float(u);
}

extern "C" void kernel_launch(void* const* d_in, const int* in_sizes, int n_in,
                              void* d_out, int out_size, void* d_ws, size_t ws_size,
                              hipStream_t stream){
    const float* x     = (const float*)d_in[0];
    const int*   ei    = (const int*)  d_in[1];
    const float* ea    = (const float*)d_in[2];
    const int*   batch = (const int*)  d_in[3];
    const float* linW  = (const float*)d_in[4];
    const float* linb  = (const float*)d_in[5];
    const float* convW = (const float*)d_in[6];
    const float* attS  = (const float*)d_in[7];
    const float* attD  = (const float*)d_in[8];
    const float* We    = (const float*)d_in[9];
    const float* attE  = (const float*)d_in[10];
    const float* convb = (const float*)d_in[11];
    const float* fc1W  = (const float*)d_in[12];
    const float* fc1b  = (const float*)d_in[13];
    const float* fc2W  = (const float*)d_in[14];
    const float* fc2b  = (const float*)d_in[15];
    const float* fc3W  = (const float*)d_in[16];
    const float* fc3b  = (const float*)d_in[17];

    int N = in_sizes[0] / 15;
    int E = in_sizes[1] / 2;

    char* w = (char*)d_ws;
    size_t o = 0;
    auto alloc = [&](size_t bytes) -> char* {
        char* p = w + o;
        o = (o + bytes + 255) & ~(size_t)255;
        return p;
    };
    double*   dsum   = (double*)  alloc(4 * 8);
    double*   Mm     = (double*)  alloc(2 * 12 * 8);
    double*   ael    = (double*)  alloc(2 * 4 * 8);
    float*    Wsrc   = (float*)   alloc(2 * 64 * 4 * 4);
    float*    Wdst   = (float*)   alloc(2 * 64 * 4 * 4);
    float*    Wt     = (float*)   alloc(2 * 256 * 64 * 4);
    unsigned* qenc   = (unsigned*)alloc(64 * 4);
    int*      deg    = (int*)     alloc((size_t)N * 4);
    int*      cursor = (int*)     alloc((size_t)N * 4);
    int*      rowptr = (int*)     alloc((size_t)(N + 1) * 4);
    int*      csum   = (int*)     alloc(64 * 4);
    int*      coff   = (int*)     alloc(64 * 4);
    int*      colsrc = (int*)     alloc((size_t)E * 4);
    int*      coldst = (int*)     alloc((size_t)E * 4);
    int*      coleid = (int*)     alloc((size_t)E * 4);
    double4*  ddbuf  = (double4*) alloc((size_t)E * 32);
    float4*   pbuf   = (float4*)  alloc((size_t)E * 16);
    unsigned long long* menc = (unsigned long long*)alloc((size_t)N * 4 * 8);
    double4*  dself  = (double4*) alloc((size_t)N * 32);
    float*    asrc   = (float*)   alloc((size_t)N * 16);
    float*    adst   = (float*)   alloc((size_t)N * 16);
    float*    hA     = (float*)   alloc((size_t)N * 256);
    float*    hB     = (float*)   alloc((size_t)N * 256);
    float*    agg    = (float*)   alloc((size_t)N * 1024);
    (void)ws_size; (void)n_in; (void)out_size;

    hipMemsetAsync(dsum, 0, 4 * 8, stream);
    hipMemsetAsync(deg, 0, (size_t)N * 4, stream);
    hipMemsetAsync(qenc, 0xFF, 64 * 4, stream);

    int nchunk = (N + 1023) / 1024;

    k_edge_stats<<<1024, 256, 0, stream>>>(ei, ea, E, dsum, deg);
    k_params<<<1, 256, 0, stream>>>(dsum, E, convW, attS, attD, We, attE, Mm, ael, Wsrc, Wdst, Wt);
    k_chunk_sum<<<nchunk, 256, 0, stream>>>(deg, N, csum);
    k_chunk_scan<<<1, 64, 0, stream>>>(csum, nchunk, coff, rowptr + N);
    k_row_ptr<<<nchunk, 1024, 0, stream>>>(deg, N, coff, rowptr, cursor);
    k_scatter<<<1024, 256, 0, stream>>>(ei, E, cursor, colsrc, coldst, coleid);

    k_lin_in<<<(N + 3) / 4, 256, 0, stream>>>(x, linW, linb, hA, N);

    int gE = (E + 255) / 256, gN = (N + 255) / 256;

    // layer 0 (no residual)
    k_attcoef<<<gN, 256, 0, stream>>>(hA, Wsrc, Wdst, asrc, adst, N);
    k_self_m<<<gN, 256, 0, stream>>>(asrc, adst, ael, dself, menc, N);
    k_edge_dd<<<gE, 256, 0, stream>>>(colsrc, coldst, coleid, ea, asrc, adst, Mm, ddbuf, menc, E);
    k_edge_p<<<gE, 256, 0, stream>>>(ddbuf, coldst, menc, pbuf, E);
    k_aggregate2<<<(N + 3) / 4, 256, 0, stream>>>(hA, dself, menc, rowptr, colsrc, pbuf, agg, N);
    k_gemm<256, false, true><<<(N + 63) / 64, 256, 0, stream>>>(agg, Wt, convb, nullptr, hB, N);

    // layer 1 (residual)
    k_attcoef<<<gN, 256, 0, stream>>>(hB, Wsrc + 256, Wdst + 256, asrc, adst, N);
    k_self_m<<<gN, 256, 0, stream>>>(asrc, adst, ael + 4, dself, menc, N);
    k_edge_dd<<<gE, 256, 0, stream>>>(colsrc, coldst, coleid, ea, asrc, adst, Mm + 12, ddbuf, menc, E);
    k_edge_p<<<gE, 256, 0, stream>>>(ddbuf, coldst, menc, pbuf, E);
    k_aggregate2<<<(N + 3) / 4, 256, 0, stream>>>(hB, dself, menc, rowptr, colsrc, pbuf, agg, N);
    k_gemm<256, true, true><<<(N + 63) / 64, 256, 0, stream>>>(agg, Wt + 16384, convb + 64, hB, hA, N);

    // fc head
    k_gemm<64, false, true><<<(N + 63) / 64, 256, 0, stream>>>(hA, fc1W, fc1b, nullptr, hB, N);
    k_gemm<64, false, true><<<(N + 63) / 64, 256, 0, stream>>>(hB, fc2W, fc2b, nullptr, hA, N);
    k_fc3<<<gN, 256, 0, stream>>>(hA, fc3W, fc3b, batch, qenc, N);
    k_qout<<<1, 64, 0, stream>>>(qenc, (float*)d_out);
}

// Round 4
// 402.018 us; speedup vs baseline: 1.4529x; 1.4529x over previous
//
#include <hip/hip_runtime.h>
#include <math.h>

// GraphQNetwork: 2-layer GAT (H=4 heads, C=64, concat=False/head-mean) + 3 FC + per-graph min.
// N=50000, E=400000, NG=64 (derived from in_sizes at launch).

__device__ __forceinline__ float gelu_f(float x){
    return 0.5f * x * (1.0f + erff(x * 0.70710678118654752f));
}

// ---------------- edge stats (mean of modified edge_attr) + in-degree histogram ----------------
__global__ void k_edge_stats(const int* __restrict__ ei, const float* __restrict__ ea,
                             int E, double* __restrict__ dsum, int* __restrict__ deg){
    __shared__ double s0[256], s1[256], s2[256];
    int t = threadIdx.x;
    double a0 = 0, a1 = 0, a2 = 0;
    for (int e = blockIdx.x * blockDim.x + t; e < E; e += gridDim.x * blockDim.x){
        float e0 = ea[e*3+0], e1 = ea[e*3+1], e2 = ea[e*3+2];
        a0 += (double)e0;
        a1 += (double)e1;
        a2 += 1.0e6 / (double)e2;   // in-place edit: 1e6 / spectral_efficiency
        atomicAdd(&deg[ei[E + e]], 1);   // dst = edge_index[1]
    }
    s0[t] = a0; s1[t] = a1; s2[t] = a2;
    __syncthreads();
    for (int off = 128; off > 0; off >>= 1){
        if (t < off){ s0[t] += s0[t+off]; s1[t] += s1[t+off]; s2[t] += s2[t+off]; }
        __syncthreads();
    }
    if (t == 0){
        atomicAdd(&dsum[0], s0[0]);
        atomicAdd(&dsum[1], s1[0]);
        atomicAdd(&dsum[2], s2[0]);
    }
}

// ---------------- tiny parameter precompute ----------------
__global__ void k_params(const double* __restrict__ dsum, int E,
                         const float* __restrict__ convW, const float* __restrict__ attS,
                         const float* __restrict__ attD, const float* __restrict__ We,
                         const float* __restrict__ attE,
                         double* __restrict__ Mm, double* __restrict__ ael,
                         float* __restrict__ Wsrc, float* __restrict__ Wdst,
                         float* __restrict__ Wt){
    int t = threadIdx.x;
    if (t < 24){
        int l = t / 12, r = t % 12, j = r / 4, h = r % 4;
        double s = 0;
        for (int c = 0; c < 64; c++)
            s += (double)We[l*768 + j*256 + h*64 + c] * (double)attE[l*256 + h*64 + c];
        Mm[l*12 + j*4 + h] = s;
    }
    __syncthreads();
    if (t < 8){
        int l = t / 4, h = t % 4;
        double s = 0;
        for (int j = 0; j < 3; j++)
            s += (dsum[j] / (double)E) * Mm[l*12 + j*4 + h];
        ael[l*4 + h] = s;
    }
    for (int idx = t; idx < 512; idx += 256){
        int l = idx >> 8, k = (idx >> 2) & 63, h = idx & 3;
        float ss = 0.f, sd = 0.f;
        for (int c = 0; c < 64; c++){
            float wv = convW[l*16384 + k*256 + h*64 + c];
            ss += wv * attS[l*256 + h*64 + c];
            sd += wv * attD[l*256 + h*64 + c];
        }
        Wsrc[idx] = ss; Wdst[idx] = sd;
    }
    for (int idx = t; idx < 32768; idx += 256){
        int l = idx >> 14, p = (idx >> 6) & 255, c = idx & 63;
        int h = p >> 6, k = p & 63;
        Wt[idx] = 0.25f * convW[l*16384 + k*256 + h*64 + c];
    }
}

// ---------------- CSR build ----------------
__global__ void k_chunk_sum(const int* __restrict__ deg, int n, int* __restrict__ csum){
    __shared__ int s[256];
    int t = threadIdx.x, base = blockIdx.x * 1024;
    int v = 0;
    for (int j = t; j < 1024; j += 256){ int i = base + j; if (i < n) v += deg[i]; }
    s[t] = v; __syncthreads();
    for (int off = 128; off > 0; off >>= 1){ if (t < off) s[t] += s[t+off]; __syncthreads(); }
    if (t == 0) csum[blockIdx.x] = s[0];
}

__global__ void k_chunk_scan(const int* __restrict__ csum, int nchunks,
                             int* __restrict__ coff, int* __restrict__ rp_end){
    if (threadIdx.x == 0){
        int run = 0;
        for (int i = 0; i < nchunks; i++){ coff[i] = run; run += csum[i]; }
        *rp_end = run;
    }
}

__global__ void __launch_bounds__(1024) k_row_ptr(const int* __restrict__ deg, int n,
                          const int* __restrict__ coff,
                          int* __restrict__ row_ptr, int* __restrict__ cursor){
    __shared__ int s[1024];
    int t = threadIdx.x, i = blockIdx.x * 1024 + t;
    int v = (i < n) ? deg[i] : 0;
    s[t] = v; __syncthreads();
    for (int off = 1; off < 1024; off <<= 1){
        int x = (t >= off) ? s[t-off] : 0;
        __syncthreads();
        s[t] += x;
        __syncthreads();
    }
    if (i < n){
        int e = coff[blockIdx.x] + s[t] - v;   // exclusive
        row_ptr[i] = e; cursor[i] = e;
    }
}

// scatter edges into CSR slots; also deposit edge features (e0,e1 f32; 1e6/e2 f64) in CSR order
__global__ void k_scatter(const int* __restrict__ ei, const float* __restrict__ ea, int E,
                          int* __restrict__ cursor, int* __restrict__ col_src,
                          float2* __restrict__ e01, double* __restrict__ e2md){
    for (int e = blockIdx.x * blockDim.x + threadIdx.x; e < E; e += gridDim.x * blockDim.x){
        int d = ei[E + e];
        int pos = atomicAdd(&cursor[d], 1);
        col_src[pos] = ei[e];
        e01[pos] = make_float2(ea[e*3+0], ea[e*3+1]);
        e2md[pos] = 1.0e6 / (double)ea[e*3+2];
    }
}

// ---------------- input projection: h = gelu(x @ linW + linb), D_IN=15 ----------------
__global__ void k_lin_in(const float* __restrict__ x, const float* __restrict__ W,
                         const float* __restrict__ b, float* __restrict__ h, int n){
    int t = threadIdx.x;
    int row = blockIdx.x * 4 + (t >> 6);
    int c = t & 63;
    if (row >= n) return;
    float acc = b[c];
    #pragma unroll
    for (int j = 0; j < 15; j++) acc += x[row*15 + j] * W[j*64 + c];
    h[row*64 + c] = gelu_f(acc);
}

// ---------------- attention coefficients: a_src/a_dst = h @ Wsrc/Wdst ([64,4]) ----------------
__global__ void k_attcoef(const float* __restrict__ h, const float* __restrict__ Wsrc,
                          const float* __restrict__ Wdst, float* __restrict__ asrc,
                          float* __restrict__ adst, int n){
    int i = blockIdx.x * blockDim.x + threadIdx.x;
    if (i >= n) return;
    const float4* h4 = (const float4*)(h + (size_t)i * 64);
    const float4* ws4 = (const float4*)Wsrc;
    const float4* wd4 = (const float4*)Wdst;
    float4 s = {0,0,0,0}, d = {0,0,0,0};
    #pragma unroll
    for (int k4 = 0; k4 < 16; k4++){
        float4 hv = h4[k4];
        float4 w;
        w = ws4[k4*4+0]; s.x += hv.x*w.x; s.y += hv.x*w.y; s.z += hv.x*w.z; s.w += hv.x*w.w;
        w = ws4[k4*4+1]; s.x += hv.y*w.x; s.y += hv.y*w.y; s.z += hv.y*w.z; s.w += hv.y*w.w;
        w = ws4[k4*4+2]; s.x += hv.z*w.x; s.y += hv.z*w.y; s.z += hv.z*w.z; s.w += hv.z*w.w;
        w = ws4[k4*4+3]; s.x += hv.w*w.x; s.y += hv.w*w.y; s.z += hv.w*w.z; s.w += hv.w*w.w;
        w = wd4[k4*4+0]; d.x += hv.x*w.x; d.y += hv.x*w.y; d.z += hv.x*w.z; d.w += hv.x*w.w;
        w = wd4[k4*4+1]; d.x += hv.y*w.x; d.y += hv.y*w.y; d.z += hv.y*w.z; d.w += hv.y*w.w;
        w = wd4[k4*4+2]; d.x += hv.z*w.x; d.y += hv.z*w.y; d.z += hv.z*w.z; d.w += hv.z*w.w;
        w = wd4[k4*4+3]; d.x += hv.w*w.x; d.y += hv.w*w.y; d.z += hv.w*w.z; d.w += hv.w*w.w;
    }
    ((float4*)asrc)[i] = s;
    ((float4*)adst)[i] = d;
}

// ---------------- fused GAT layer: wave per node, lanes over edges for logits/max,
// lane-per-channel for aggregation. No atomics, no per-edge global buffers. ----------------
__global__ void __launch_bounds__(256) k_gat(const float* __restrict__ hin,
                     const float* __restrict__ asrc, const float* __restrict__ adst,
                     const int* __restrict__ row_ptr, const int* __restrict__ col_src,
                     const float2* __restrict__ e01, const double* __restrict__ e2md,
                     const double* __restrict__ Mm, const double* __restrict__ ael,
                     float* __restrict__ agg, int n){
    __shared__ float s_pf[4][64][4];
    __shared__ int   s_sj[4][64];
    int w = threadIdx.x >> 6, lane = threadIdx.x & 63;
    int i = blockIdx.x * 4 + w;
    if (i >= n) return;

    double M0[4], M1[4], M2[4];
    #pragma unroll
    for (int h = 0; h < 4; h++){ M0[h]=Mm[h]; M1[h]=Mm[4+h]; M2[h]=Mm[8+h]; }

    float4 av = ((const float4*)asrc)[i];
    float4 bv = ((const float4*)adst)[i];
    float as_i[4] = {av.x, av.y, av.z, av.w};
    double ad[4]  = {(double)bv.x, (double)bv.y, (double)bv.z, (double)bv.w};

    // self-loop logit (reference association: (a_src + a_dst) + a_e)
    double ddS[4];
    #pragma unroll
    for (int h = 0; h < 4; h++){
        double x = ((double)as_i[h] + ad[h]) + ael[h];
        if (x < 0.0) x *= 0.2;
        ddS[h] = x;
    }

    int r0 = row_ptr[i], r1 = row_ptr[i+1];
    int deg = r1 - r0;

    // chunk 0 (covers deg<=64, the common case) — keep dd in registers
    double dd0[4];
    int s0 = 0;
    bool have0 = lane < deg;
    double mloc[4] = {-1e300, -1e300, -1e300, -1e300};
    if (have0){
        int p = r0 + lane;
        float2 ab = e01[p];
        double em = e2md[p];
        int s = col_src[p]; s0 = s;
        float4 sv = ((const float4*)asrc)[s];
        float ss[4] = {sv.x, sv.y, sv.z, sv.w};
        #pragma unroll
        for (int h = 0; h < 4; h++){
            double aeh = (double)ab.x*M0[h] + (double)ab.y*M1[h] + em*M2[h];
            double x = ((double)ss[h] + ad[h]) + aeh;
            if (x < 0.0) x *= 0.2;
            dd0[h] = x; mloc[h] = x;
        }
    }
    // rare extra chunks: max only
    for (int base = r0 + 64; base < r1; base += 64){
        int p = base + lane;
        if (p < r1){
            float2 ab = e01[p];
            double em = e2md[p];
            int s = col_src[p];
            float4 sv = ((const float4*)asrc)[s];
            float ss[4] = {sv.x, sv.y, sv.z, sv.w};
            #pragma unroll
            for (int h = 0; h < 4; h++){
                double aeh = (double)ab.x*M0[h] + (double)ab.y*M1[h] + em*M2[h];
                double x = ((double)ss[h] + ad[h]) + aeh;
                if (x < 0.0) x *= 0.2;
                mloc[h] = fmax(mloc[h], x);
            }
        }
    }
    // wave max-reduce (f64), fold in self-loop
    double m[4];
    #pragma unroll
    for (int h = 0; h < 4; h++){
        double v = mloc[h];
        #pragma unroll
        for (int off = 32; off > 0; off >>= 1)
            v = fmax(v, __shfl_xor(v, off));
        m[h] = fmax(ddS[h], v);
    }

    float hself = hin[(size_t)i*64 + lane];
    float ssum[4], acc[4];
    #pragma unroll
    for (int h = 0; h < 4; h++){
        float ps = expf((float)(ddS[h] - m[h]));
        ssum[h] = ps; acc[h] = ps * hself;
    }

    // chunk 0 accumulate: p via LDS broadcast, lane = channel
    {
        float4 pf = {0.f, 0.f, 0.f, 0.f};
        if (have0){
            pf.x = expf((float)(dd0[0] - m[0]));
            pf.y = expf((float)(dd0[1] - m[1]));
            pf.z = expf((float)(dd0[2] - m[2]));
            pf.w = expf((float)(dd0[3] - m[3]));
        }
        *(float4*)&s_pf[w][lane][0] = pf;
        s_sj[w][lane] = s0;
        int len = deg < 64 ? deg : 64;
        for (int j = 0; j < len; j++){
            float4 p4 = *(const float4*)&s_pf[w][j][0];
            int sj = s_sj[w][j];
            float hv = hin[(size_t)sj*64 + lane];
            acc[0] += p4.x * hv; ssum[0] += p4.x;
            acc[1] += p4.y * hv; ssum[1] += p4.y;
            acc[2] += p4.z * hv; ssum[2] += p4.z;
            acc[3] += p4.w * hv; ssum[3] += p4.w;
        }
    }
    // rare extra chunks: recompute dd -> p -> accumulate
    for (int base = r0 + 64; base < r1; base += 64){
        int p = base + lane;
        float4 pf = {0.f, 0.f, 0.f, 0.f};
        int sx = 0;
        if (p < r1){
            float2 ab = e01[p];
            double em = e2md[p];
            int s = col_src[p]; sx = s;
            float4 sv = ((const float4*)asrc)[s];
            float ss[4] = {sv.x, sv.y, sv.z, sv.w};
            float pp[4];
            #pragma unroll
            for (int h = 0; h < 4; h++){
                double aeh = (double)ab.x*M0[h] + (double)ab.y*M1[h] + em*M2[h];
                double x = ((double)ss[h] + ad[h]) + aeh;
                if (x < 0.0) x *= 0.2;
                pp[h] = expf((float)(x - m[h]));
            }
            pf.x = pp[0]; pf.y = pp[1]; pf.z = pp[2]; pf.w = pp[3];
        }
        *(float4*)&s_pf[w][lane][0] = pf;
        s_sj[w][lane] = sx;
        int len = (r1 - base) < 64 ? (r1 - base) : 64;
        for (int j = 0; j < len; j++){
            float4 p4 = *(const float4*)&s_pf[w][j][0];
            int sj = s_sj[w][j];
            float hv = hin[(size_t)sj*64 + lane];
            acc[0] += p4.x * hv; ssum[0] += p4.x;
            acc[1] += p4.y * hv; ssum[1] += p4.y;
            acc[2] += p4.z * hv; ssum[2] += p4.z;
            acc[3] += p4.w * hv; ssum[3] += p4.w;
        }
    }

    #pragma unroll
    for (int h = 0; h < 4; h++){
        float inv = 1.0f / (ssum[h] + 1e-16f);
        agg[(size_t)i*256 + h*64 + lane] = acc[h] * inv;
    }
}

// ---------------- tiled GEMM: out[n,64] = act(A[n,K] @ B[K,64] + bias (+res)) ----------------
template<int K, bool RES, bool GEL>
__global__ void __launch_bounds__(256) k_gemm(const float* __restrict__ A, const float* __restrict__ B,
                      const float* __restrict__ bias, const float* __restrict__ res,
                      float* __restrict__ out, int n){
    __shared__ float Bs[K * 64];
    int t = threadIdx.x;
    for (int idx = t; idx < K*64; idx += 256) Bs[idx] = B[idx];
    __syncthreads();

    int row0 = blockIdx.x * 64;
    int tr = t >> 4, tc = t & 15;
    int r = row0 + tr*4;
    int c = tc*4;
    float acc[4][4] = {};

    int rr[4];
    #pragma unroll
    for (int i = 0; i < 4; i++){ int q = r + i; rr[i] = (q < n) ? q : (n - 1); }

    const float4* A4 = (const float4*)A;
    for (int k4 = 0; k4 < K/4; k4++){
        float4 b0 = *(const float4*)&Bs[(k4*4+0)*64 + c];
        float4 b1 = *(const float4*)&Bs[(k4*4+1)*64 + c];
        float4 b2 = *(const float4*)&Bs[(k4*4+2)*64 + c];
        float4 b3 = *(const float4*)&Bs[(k4*4+3)*64 + c];
        #pragma unroll
        for (int i = 0; i < 4; i++){
            float4 a = A4[(size_t)rr[i]*(K/4) + k4];
            acc[i][0] += a.x*b0.x + a.y*b1.x + a.z*b2.x + a.w*b3.x;
            acc[i][1] += a.x*b0.y + a.y*b1.y + a.z*b2.y + a.w*b3.y;
            acc[i][2] += a.x*b0.z + a.y*b1.z + a.z*b2.z + a.w*b3.z;
            acc[i][3] += a.x*b0.w + a.y*b1.w + a.z*b2.w + a.w*b3.w;
        }
    }

    float4 bb = *(const float4*)&bias[c];
    #pragma unroll
    for (int i = 0; i < 4; i++){
        int q = r + i;
        if (q < n){
            float4 v;
            v.x = acc[i][0] + bb.x; v.y = acc[i][1] + bb.y;
            v.z = acc[i][2] + bb.z; v.w = acc[i][3] + bb.w;
            if (RES){
                float4 rv = *(const float4*)&res[(size_t)q*64 + c];
                v.x += rv.x; v.y += rv.y; v.z += rv.z; v.w += rv.w;
            }
            if (GEL){
                v.x = gelu_f(v.x); v.y = gelu_f(v.y);
                v.z = gelu_f(v.z); v.w = gelu_f(v.w);
            }
            *(float4*)&out[(size_t)q*64 + c] = v;
        }
    }
}

// ---------------- fc3 + per-graph min (hierarchical: wave -> LDS -> global) ----------------
__global__ void k_fc3(const float* __restrict__ h, const float* __restrict__ W,
                      const float* __restrict__ b, const int* __restrict__ batch,
                      unsigned int* __restrict__ qenc, int n){
    __shared__ unsigned smin[64];
    int t = threadIdx.x;
    if (t < 64) smin[t] = 0xFFFFFFFFu;
    __syncthreads();

    int i = blockIdx.x * blockDim.x + t;
    unsigned u = 0xFFFFFFFFu;
    int g = -1;
    if (i < n){
        float q = b[0];
        const float4* h4 = (const float4*)(h + (size_t)i*64);
        const float4* w4 = (const float4*)W;
        #pragma unroll
        for (int k = 0; k < 16; k++){
            float4 hv = h4[k], wv = w4[k];
            q += hv.x*wv.x + hv.y*wv.y + hv.z*wv.z + hv.w*wv.w;
        }
        unsigned enc = __float_as_uint(q);
        u = (enc & 0x80000000u) ? ~enc : (enc | 0x80000000u);   // order-preserving encode
        g = batch[i];
    }
    int g0 = __shfl(g, 0);
    bool uni = __all(g == g0);
    if (uni){
        #pragma unroll
        for (int off = 32; off > 0; off >>= 1){
            unsigned o = __shfl_xor(u, off);
            u = (o < u) ? o : u;
        }
        if ((t & 63) == 0 && g0 >= 0) atomicMin(&smin[g0], u);
    } else if (i < n){
        atomicMin(&smin[g], u);
    }
    __syncthreads();
    if (t < 64 && smin[t] != 0xFFFFFFFFu) atomicMin(&qenc[t], smin[t]);
}

__global__ void k_qout(const unsigned int* __restrict__ qenc, float* __restrict__ out){
    int g = threadIdx.x;
    unsigned u = qenc[g];
    u = (u & 0x80000000u) ? (u & 0x7FFFFFFFu) : ~u;   // decode
    out[g] = __uint_as_float(u);
}

extern "C" void kernel_launch(void* const* d_in, const int* in_sizes, int n_in,
                              void* d_out, int out_size, void* d_ws, size_t ws_size,
                              hipStream_t stream){
    const float* x     = (const float*)d_in[0];
    const int*   ei    = (const int*)  d_in[1];
    const float* ea    = (const float*)d_in[2];
    const int*   batch = (const int*)  d_in[3];
    const float* linW  = (const float*)d_in[4];
    const float* linb  = (const float*)d_in[5];
    const float* convW = (const float*)d_in[6];
    const float* attS  = (const float*)d_in[7];
    const float* attD  = (const float*)d_in[8];
    const float* We    = (const float*)d_in[9];
    const float* attE  = (const float*)d_in[10];
    const float* convb = (const float*)d_in[11];
    const float* fc1W  = (const float*)d_in[12];
    const float* fc1b  = (const float*)d_in[13];
    const float* fc2W  = (const float*)d_in[14];
    const float* fc2b  = (const float*)d_in[15];
    const float* fc3W  = (const float*)d_in[16];
    const float* fc3b  = (const float*)d_in[17];

    int N = in_sizes[0] / 15;
    int E = in_sizes[1] / 2;

    char* w = (char*)d_ws;
    size_t o = 0;
    auto alloc = [&](size_t bytes) -> char* {
        char* p = w + o;
        o = (o + bytes + 255) & ~(size_t)255;
        return p;
    };
    double*   dsum   = (double*)  alloc(4 * 8);
    double*   Mm     = (double*)  alloc(2 * 12 * 8);
    double*   ael    = (double*)  alloc(2 * 4 * 8);
    float*    Wsrc   = (float*)   alloc(2 * 64 * 4 * 4);
    float*    Wdst   = (float*)   alloc(2 * 64 * 4 * 4);
    float*    Wt     = (float*)   alloc(2 * 256 * 64 * 4);
    unsigned* qenc   = (unsigned*)alloc(64 * 4);
    int*      deg    = (int*)     alloc((size_t)N * 4);
    int*      cursor = (int*)     alloc((size_t)N * 4);
    int*      rowptr = (int*)     alloc((size_t)(N + 1) * 4);
    int*      csum   = (int*)     alloc(64 * 4);
    int*      coff   = (int*)     alloc(64 * 4);
    int*      colsrc = (int*)     alloc((size_t)E * 4);
    float2*   e01    = (float2*)  alloc((size_t)E * 8);
    double*   e2md   = (double*)  alloc((size_t)E * 8);
    float*    asrc   = (float*)   alloc((size_t)N * 16);
    float*    adst   = (float*)   alloc((size_t)N * 16);
    float*    hA     = (float*)   alloc((size_t)N * 256);
    float*    hB     = (float*)   alloc((size_t)N * 256);
    float*    agg    = (float*)   alloc((size_t)N * 1024);
    (void)ws_size; (void)n_in; (void)out_size;

    hipMemsetAsync(dsum, 0, 4 * 8, stream);
    hipMemsetAsync(deg, 0, (size_t)N * 4, stream);
    hipMemsetAsync(qenc, 0xFF, 64 * 4, stream);

    int nchunk = (N + 1023) / 1024;

    k_edge_stats<<<1024, 256, 0, stream>>>(ei, ea, E, dsum, deg);
    k_params<<<1, 256, 0, stream>>>(dsum, E, convW, attS, attD, We, attE, Mm, ael, Wsrc, Wdst, Wt);
    k_chunk_sum<<<nchunk, 256, 0, stream>>>(deg, N, csum);
    k_chunk_scan<<<1, 64, 0, stream>>>(csum, nchunk, coff, rowptr + N);
    k_row_ptr<<<nchunk, 1024, 0, stream>>>(deg, N, coff, rowptr, cursor);
    k_scatter<<<1024, 256, 0, stream>>>(ei, ea, E, cursor, colsrc, e01, e2md);

    k_lin_in<<<(N + 3) / 4, 256, 0, stream>>>(x, linW, linb, hA, N);

    int gN = (N + 255) / 256, gW = (N + 3) / 4;

    // layer 0 (no residual)
    k_attcoef<<<gN, 256, 0, stream>>>(hA, Wsrc, Wdst, asrc, adst, N);
    k_gat<<<gW, 256, 0, stream>>>(hA, asrc, adst, rowptr, colsrc, e01, e2md, Mm, ael, agg, N);
    k_gemm<256, false, true><<<(N + 63) / 64, 256, 0, stream>>>(agg, Wt, convb, nullptr, hB, N);

    // layer 1 (residual)
    k_attcoef<<<gN, 256, 0, stream>>>(hB, Wsrc + 256, Wdst + 256, asrc, adst, N);
    k_gat<<<gW, 256, 0, stream>>>(hB, asrc, adst, rowptr, colsrc, e01, e2md, Mm + 12, ael + 4, agg, N);
    k_gemm<256, true, true><<<(N + 63) / 64, 256, 0, stream>>>(agg, Wt + 16384, convb + 64, hB, hA, N);

    // fc head
    k_gemm<64, false, true><<<(N + 63) / 64, 256, 0, stream>>>(hA, fc1W, fc1b, nullptr, hB, N);
    k_gemm<64, false, true><<<(N + 63) / 64, 256, 0, stream>>>(hB, fc2W, fc2b, nullptr, hA, N);
    k_fc3<<<gN, 256, 0, stream>>>(hA, fc3W, fc3b, batch, qenc, N);
    k_qout<<<1, 64, 0, stream>>>(qenc, (float*)d_out);
}

// Round 5
// 373.682 us; speedup vs baseline: 1.5631x; 1.0758x over previous
//
#include <hip/hip_runtime.h>
#include <math.h>

// GraphQNetwork: 2-layer GAT (H=4 heads, C=64, concat=False/head-mean) + 3 FC + per-graph min.
// N=50000, E=400000, NG=64 (derived from in_sizes at launch).

__device__ __forceinline__ float gelu_f(float x){
    return 0.5f * x * (1.0f + erff(x * 0.70710678118654752f));
}

__device__ __forceinline__ unsigned enc_f(float q){
    unsigned u = __float_as_uint(q);
    return (u & 0x80000000u) ? ~u : (u | 0x80000000u);   // order-preserving encode
}

// ---------------- edge stats (mean of modified edge_attr) + in-degree histogram ----------------
__global__ void k_edge_stats(const int* __restrict__ ei, const float* __restrict__ ea,
                             int E, double* __restrict__ dsum, int* __restrict__ deg){
    __shared__ double s0[256], s1[256], s2[256];
    int t = threadIdx.x;
    double a0 = 0, a1 = 0, a2 = 0;
    for (int e = blockIdx.x * blockDim.x + t; e < E; e += gridDim.x * blockDim.x){
        float e0 = ea[e*3+0], e1 = ea[e*3+1], e2 = ea[e*3+2];
        a0 += (double)e0;
        a1 += (double)e1;
        a2 += 1.0e6 / (double)e2;   // in-place edit: 1e6 / spectral_efficiency
        atomicAdd(&deg[ei[E + e]], 1);   // dst = edge_index[1]
    }
    s0[t] = a0; s1[t] = a1; s2[t] = a2;
    __syncthreads();
    for (int off = 128; off > 0; off >>= 1){
        if (t < off){ s0[t] += s0[t+off]; s1[t] += s1[t+off]; s2[t] += s2[t+off]; }
        __syncthreads();
    }
    if (t == 0){
        atomicAdd(&dsum[0], s0[0]);
        atomicAdd(&dsum[1], s1[0]);
        atomicAdd(&dsum[2], s2[0]);
    }
}

// ---------------- tiny parameter precompute ----------------
__global__ void k_params(const double* __restrict__ dsum, int E,
                         const float* __restrict__ convW, const float* __restrict__ attS,
                         const float* __restrict__ attD, const float* __restrict__ We,
                         const float* __restrict__ attE,
                         double* __restrict__ Mm, double* __restrict__ ael,
                         float* __restrict__ Wsrc, float* __restrict__ Wdst,
                         float* __restrict__ Wt){
    int t = threadIdx.x;
    if (t < 24){
        int l = t / 12, r = t % 12, j = r / 4, h = r % 4;
        double s = 0;
        for (int c = 0; c < 64; c++)
            s += (double)We[l*768 + j*256 + h*64 + c] * (double)attE[l*256 + h*64 + c];
        Mm[l*12 + j*4 + h] = s;
    }
    __syncthreads();
    if (t < 8){
        int l = t / 4, h = t % 4;
        double s = 0;
        for (int j = 0; j < 3; j++)
            s += (dsum[j] / (double)E) * Mm[l*12 + j*4 + h];
        ael[l*4 + h] = s;
    }
    for (int idx = t; idx < 512; idx += 256){
        int l = idx >> 8, k = (idx >> 2) & 63, h = idx & 3;
        float ss = 0.f, sd = 0.f;
        for (int c = 0; c < 64; c++){
            float wv = convW[l*16384 + k*256 + h*64 + c];
            ss += wv * attS[l*256 + h*64 + c];
            sd += wv * attD[l*256 + h*64 + c];
        }
        Wsrc[idx] = ss; Wdst[idx] = sd;
    }
    for (int idx = t; idx < 32768; idx += 256){
        int l = idx >> 14, p = (idx >> 6) & 255, c = idx & 63;
        int h = p >> 6, k = p & 63;
        Wt[idx] = 0.25f * convW[l*16384 + k*256 + h*64 + c];
    }
}

// ---------------- CSR build ----------------
__global__ void k_chunk_sum(const int* __restrict__ deg, int n, int* __restrict__ csum){
    __shared__ int s[256];
    int t = threadIdx.x, base = blockIdx.x * 1024;
    int v = 0;
    for (int j = t; j < 1024; j += 256){ int i = base + j; if (i < n) v += deg[i]; }
    s[t] = v; __syncthreads();
    for (int off = 128; off > 0; off >>= 1){ if (t < off) s[t] += s[t+off]; __syncthreads(); }
    if (t == 0) csum[blockIdx.x] = s[0];
}

__global__ void k_chunk_scan(const int* __restrict__ csum, int nchunks,
                             int* __restrict__ coff, int* __restrict__ rp_end){
    if (threadIdx.x == 0){
        int run = 0;
        for (int i = 0; i < nchunks; i++){ coff[i] = run; run += csum[i]; }
        *rp_end = run;
    }
}

__global__ void __launch_bounds__(1024) k_row_ptr(const int* __restrict__ deg, int n,
                          const int* __restrict__ coff,
                          int* __restrict__ row_ptr, int* __restrict__ cursor){
    __shared__ int s[1024];
    int t = threadIdx.x, i = blockIdx.x * 1024 + t;
    int v = (i < n) ? deg[i] : 0;
    s[t] = v; __syncthreads();
    for (int off = 1; off < 1024; off <<= 1){
        int x = (t >= off) ? s[t-off] : 0;
        __syncthreads();
        s[t] += x;
        __syncthreads();
    }
    if (i < n){
        int e = coff[blockIdx.x] + s[t] - v;   // exclusive
        row_ptr[i] = e; cursor[i] = e;
    }
}

// scatter edges into CSR slots; also deposit edge features (e0,e1 f32; 1e6/e2 f64) in CSR order
__global__ void k_scatter(const int* __restrict__ ei, const float* __restrict__ ea, int E,
                          int* __restrict__ cursor, int* __restrict__ col_src,
                          float2* __restrict__ e01, double* __restrict__ e2md){
    for (int e = blockIdx.x * blockDim.x + threadIdx.x; e < E; e += gridDim.x * blockDim.x){
        int d = ei[E + e];
        int pos = atomicAdd(&cursor[d], 1);
        col_src[pos] = ei[e];
        e01[pos] = make_float2(ea[e*3+0], ea[e*3+1]);
        e2md[pos] = 1.0e6 / (double)ea[e*3+2];
    }
}

// ---------------- input projection: h = gelu(x @ linW + linb), D_IN=15 ----------------
__global__ void k_lin_in(const float* __restrict__ x, const float* __restrict__ W,
                         const float* __restrict__ b, float* __restrict__ h, int n){
    int t = threadIdx.x;
    int row = blockIdx.x * 4 + (t >> 6);
    int c = t & 63;
    if (row >= n) return;
    float acc = b[c];
    #pragma unroll
    for (int j = 0; j < 15; j++) acc += x[row*15 + j] * W[j*64 + c];
    h[row*64 + c] = gelu_f(acc);
}

// ---------------- attention coefficients: a_src/a_dst = h @ Wsrc/Wdst ([64,4]) ----------------
__global__ void k_attcoef(const float* __restrict__ h, const float* __restrict__ Wsrc,
                          const float* __restrict__ Wdst, float* __restrict__ asrc,
                          float* __restrict__ adst, int n){
    int i = blockIdx.x * blockDim.x + threadIdx.x;
    if (i >= n) return;
    const float4* h4 = (const float4*)(h + (size_t)i * 64);
    const float4* ws4 = (const float4*)Wsrc;
    const float4* wd4 = (const float4*)Wdst;
    float4 s = {0,0,0,0}, d = {0,0,0,0};
    #pragma unroll
    for (int k4 = 0; k4 < 16; k4++){
        float4 hv = h4[k4];
        float4 w;
        w = ws4[k4*4+0]; s.x += hv.x*w.x; s.y += hv.x*w.y; s.z += hv.x*w.z; s.w += hv.x*w.w;
        w = ws4[k4*4+1]; s.x += hv.y*w.x; s.y += hv.y*w.y; s.z += hv.y*w.z; s.w += hv.y*w.w;
        w = ws4[k4*4+2]; s.x += hv.z*w.x; s.y += hv.z*w.y; s.z += hv.z*w.z; s.w += hv.z*w.w;
        w = ws4[k4*4+3]; s.x += hv.w*w.x; s.y += hv.w*w.y; s.z += hv.w*w.z; s.w += hv.w*w.w;
        w = wd4[k4*4+0]; d.x += hv.x*w.x; d.y += hv.x*w.y; d.z += hv.x*w.z; d.w += hv.x*w.w;
        w = wd4[k4*4+1]; d.x += hv.y*w.x; d.y += hv.y*w.y; d.z += hv.y*w.z; d.w += hv.y*w.w;
        w = wd4[k4*4+2]; d.x += hv.z*w.x; d.y += hv.z*w.y; d.z += hv.z*w.z; d.w += hv.z*w.w;
        w = wd4[k4*4+3]; d.x += hv.w*w.x; d.y += hv.w*w.y; d.z += hv.w*w.z; d.w += hv.w*w.w;
    }
    ((float4*)asrc)[i] = s;
    ((float4*)adst)[i] = d;
}

// ---------------- fused GAT layer v2: wave per node.
// Phase 1: lane = (edge j = lane>>2, head h = lane&3) -> 16 edges/pass, f64 logits,
//          butterfly max + butterfly ssum over j-strides {4,8,16,32}.
// Phase 2: lane = channel; src row base hoisted to SGPR via readfirstlane. ----------------
__global__ void __launch_bounds__(256) k_gat(const float* __restrict__ hin,
                     const float* __restrict__ asrc, const float* __restrict__ adst,
                     const int* __restrict__ row_ptr, const int* __restrict__ col_src,
                     const float2* __restrict__ e01, const double* __restrict__ e2md,
                     const double* __restrict__ Mm, const double* __restrict__ ael,
                     float* __restrict__ agg, int n){
    __shared__ float s_p[4][64][4];   // [wave][edge slot][head]
    __shared__ int   s_sj[4][64];
    __shared__ float s_meta[4][8];    // [wave][pself(4) | inv(4)]
    int w = threadIdx.x >> 6, lane = threadIdx.x & 63;
    int i = blockIdx.x * 4 + w;
    if (i >= n) return;
    int j = lane >> 2, h = lane & 3;

    double M0 = Mm[h], M1 = Mm[4+h], M2 = Mm[8+h];
    double adh = (double)adst[(size_t)i*4 + h];
    double ash = (double)asrc[(size_t)i*4 + h];
    double ddS = (ash + adh) + ael[h];
    if (ddS < 0.0) ddS *= 0.2;

    int r0 = row_ptr[i], r1 = row_ptr[i+1];
    int deg = r1 - r0;

    auto edge_logit = [&](int p) -> double {
        float2 ab = e01[p];
        double em = e2md[p];
        int s = col_src[p];
        float ssh = asrc[(size_t)s*4 + h];
        double aeh = (double)ab.x*M0 + (double)ab.y*M1 + em*M2;
        double xx = ((double)ssh + adh) + aeh;
        return (xx < 0.0) ? xx * 0.2 : xx;
    };

    // ---- max phase ----
    bool fast = (deg <= 16);
    double dd0 = 0.0;
    double mloc = ddS;
    if (fast){
        if (j < deg){
            dd0 = edge_logit(r0 + j);
            mloc = fmax(mloc, dd0);
        }
    } else {
        for (int p = r0 + j; p < r1; p += 16)
            mloc = fmax(mloc, edge_logit(p));
    }
    #pragma unroll
    for (int off = 4; off < 64; off <<= 1)
        mloc = fmax(mloc, __shfl_xor(mloc, off));
    double m = mloc;

    float pself = expf((float)(ddS - m));
    if (lane < 4) s_meta[w][lane] = pself;          // lane==h for lane<4
    float4 ps4 = *(const float4*)&s_meta[w][0];

    float hself = hin[(size_t)i*64 + lane];
    float acc0 = ps4.x * hself, acc1 = ps4.y * hself;
    float acc2 = ps4.z * hself, acc3 = ps4.w * hself;
    float ssumh = 0.f;

    // ---- superchunks of 64 edges: p-fill (edge-head ctx) then accumulate (channel ctx) ----
    for (int base = r0; base < r1; base += 64){
        int rem = r1 - base;
        int cnt = rem < 64 ? rem : 64;
        for (int q = 0; q < cnt; q += 16){
            int idx = q + j;
            float pf = 0.f; int sv = 0;
            if (idx < cnt){
                int p = base + idx;
                double xx = fast ? dd0 : edge_logit(p);
                pf = expf((float)(xx - m));
                sv = col_src[p];
                ssumh += pf;
            }
            s_p[w][idx][h] = pf;
            if (h == 0) s_sj[w][idx] = sv;
        }
        int jj = 0;
        for (; jj + 1 < cnt; jj += 2){
            int sa = __builtin_amdgcn_readfirstlane(s_sj[w][jj]);
            int sb = __builtin_amdgcn_readfirstlane(s_sj[w][jj+1]);
            float4 pa = *(const float4*)&s_p[w][jj][0];
            float4 pb = *(const float4*)&s_p[w][jj+1][0];
            float ha = hin[(size_t)sa*64 + lane];
            float hb = hin[(size_t)sb*64 + lane];
            acc0 += pa.x*ha; acc1 += pa.y*ha; acc2 += pa.z*ha; acc3 += pa.w*ha;
            acc0 += pb.x*hb; acc1 += pb.y*hb; acc2 += pb.z*hb; acc3 += pb.w*hb;
        }
        if (jj < cnt){
            int sa = __builtin_amdgcn_readfirstlane(s_sj[w][jj]);
            float4 pa = *(const float4*)&s_p[w][jj][0];
            float ha = hin[(size_t)sa*64 + lane];
            acc0 += pa.x*ha; acc1 += pa.y*ha; acc2 += pa.z*ha; acc3 += pa.w*ha;
        }
    }

    // ---- total ssum per head (butterfly over j) + self, then inv ----
    #pragma unroll
    for (int off = 4; off < 64; off <<= 1)
        ssumh += __shfl_xor(ssumh, off);
    ssumh += pself;
    if (lane < 4) s_meta[w][4 + lane] = 1.0f / (ssumh + 1e-16f);
    float4 inv4 = *(const float4*)&s_meta[w][4];

    float* orow = agg + (size_t)i*256 + lane;
    orow[0]   = acc0 * inv4.x;
    orow[64]  = acc1 * inv4.y;
    orow[128] = acc2 * inv4.z;
    orow[192] = acc3 * inv4.w;
}

// ---------------- tiled GEMM: out[n,64] = act(A[n,K] @ B[K,64] + bias (+res)) ----------------
template<int K, bool RES, bool GEL>
__global__ void __launch_bounds__(256) k_gemm(const float* __restrict__ A, const float* __restrict__ B,
                      const float* __restrict__ bias, const float* __restrict__ res,
                      float* __restrict__ out, int n){
    __shared__ float Bs[K * 64];
    int t = threadIdx.x;
    for (int idx = t; idx < K*64; idx += 256) Bs[idx] = B[idx];
    __syncthreads();

    int row0 = blockIdx.x * 64;
    int tr = t >> 4, tc = t & 15;
    int r = row0 + tr*4;
    int c = tc*4;
    float acc[4][4] = {};

    int rr[4];
    #pragma unroll
    for (int i = 0; i < 4; i++){ int q = r + i; rr[i] = (q < n) ? q : (n - 1); }

    const float4* A4 = (const float4*)A;
    for (int k4 = 0; k4 < K/4; k4++){
        float4 b0 = *(const float4*)&Bs[(k4*4+0)*64 + c];
        float4 b1 = *(const float4*)&Bs[(k4*4+1)*64 + c];
        float4 b2 = *(const float4*)&Bs[(k4*4+2)*64 + c];
        float4 b3 = *(const float4*)&Bs[(k4*4+3)*64 + c];
        #pragma unroll
        for (int i = 0; i < 4; i++){
            float4 a = A4[(size_t)rr[i]*(K/4) + k4];
            acc[i][0] += a.x*b0.x + a.y*b1.x + a.z*b2.x + a.w*b3.x;
            acc[i][1] += a.x*b0.y + a.y*b1.y + a.z*b2.y + a.w*b3.y;
            acc[i][2] += a.x*b0.z + a.y*b1.z + a.z*b2.z + a.w*b3.z;
            acc[i][3] += a.x*b0.w + a.y*b1.w + a.z*b2.w + a.w*b3.w;
        }
    }

    float4 bb = *(const float4*)&bias[c];
    #pragma unroll
    for (int i = 0; i < 4; i++){
        int q = r + i;
        if (q < n){
            float4 v;
            v.x = acc[i][0] + bb.x; v.y = acc[i][1] + bb.y;
            v.z = acc[i][2] + bb.z; v.w = acc[i][3] + bb.w;
            if (RES){
                float4 rv = *(const float4*)&res[(size_t)q*64 + c];
                v.x += rv.x; v.y += rv.y; v.z += rv.z; v.w += rv.w;
            }
            if (GEL){
                v.x = gelu_f(v.x); v.y = gelu_f(v.y);
                v.z = gelu_f(v.z); v.w = gelu_f(v.w);
            }
            *(float4*)&out[(size_t)q*64 + c] = v;
        }
    }
}

// ---------------- fused FC head: gelu(fc1) -> gelu(fc2) -> fc3 dot -> per-graph min ----------------
__global__ void __launch_bounds__(256) k_fc(const float* __restrict__ A,
                    const float* __restrict__ W1, const float* __restrict__ b1,
                    const float* __restrict__ W2, const float* __restrict__ b2,
                    const float* __restrict__ W3, const float* __restrict__ b3,
                    const int* __restrict__ batch, unsigned int* __restrict__ qenc, int n){
    __shared__ float Ws1[64*64];
    __shared__ float Ws2[64*64];
    __shared__ float mid[64*68];      // padded stride 68 to break bank aliasing
    __shared__ float w3s[64];
    __shared__ unsigned smin[64];
    int t = threadIdx.x;
    for (int idx = t; idx < 4096; idx += 256){ Ws1[idx] = W1[idx]; Ws2[idx] = W2[idx]; }
    if (t < 64){ w3s[t] = W3[t]; smin[t] = 0xFFFFFFFFu; }
    __syncthreads();

    int row0 = blockIdx.x * 64;
    int tr = t >> 4, tc = t & 15;
    int r = row0 + tr*4, c = tc*4;
    int rr[4];
    #pragma unroll
    for (int i = 0; i < 4; i++){ int q = r + i; rr[i] = (q < n) ? q : (n - 1); }

    // fc1
    float acc[4][4] = {};
    const float4* A4 = (const float4*)A;
    for (int k4 = 0; k4 < 16; k4++){
        float4 b0 = *(const float4*)&Ws1[(k4*4+0)*64 + c];
        float4 b1v = *(const float4*)&Ws1[(k4*4+1)*64 + c];
        float4 b2v = *(const float4*)&Ws1[(k4*4+2)*64 + c];
        float4 b3v = *(const float4*)&Ws1[(k4*4+3)*64 + c];
        #pragma unroll
        for (int i = 0; i < 4; i++){
            float4 a = A4[(size_t)rr[i]*16 + k4];
            acc[i][0] += a.x*b0.x + a.y*b1v.x + a.z*b2v.x + a.w*b3v.x;
            acc[i][1] += a.x*b0.y + a.y*b1v.y + a.z*b2v.y + a.w*b3v.y;
            acc[i][2] += a.x*b0.z + a.y*b1v.z + a.z*b2v.z + a.w*b3v.z;
            acc[i][3] += a.x*b0.w + a.y*b1v.w + a.z*b2v.w + a.w*b3v.w;
        }
    }
    float4 bb1 = *(const float4*)&b1[c];
    #pragma unroll
    for (int i = 0; i < 4; i++){
        float4 v;
        v.x = gelu_f(acc[i][0] + bb1.x); v.y = gelu_f(acc[i][1] + bb1.y);
        v.z = gelu_f(acc[i][2] + bb1.z); v.w = gelu_f(acc[i][3] + bb1.w);
        *(float4*)&mid[(tr*4+i)*68 + c] = v;
    }
    __syncthreads();

    // fc2
    float acc2[4][4] = {};
    for (int k4 = 0; k4 < 16; k4++){
        float4 b0 = *(const float4*)&Ws2[(k4*4+0)*64 + c];
        float4 b1v = *(const float4*)&Ws2[(k4*4+1)*64 + c];
        float4 b2v = *(const float4*)&Ws2[(k4*4+2)*64 + c];
        float4 b3v = *(const float4*)&Ws2[(k4*4+3)*64 + c];
        #pragma unroll
        for (int i = 0; i < 4; i++){
            float4 a = *(const float4*)&mid[(tr*4+i)*68 + k4*4];
            acc2[i][0] += a.x*b0.x + a.y*b1v.x + a.z*b2v.x + a.w*b3v.x;
            acc2[i][1] += a.x*b0.y + a.y*b1v.y + a.z*b2v.y + a.w*b3v.y;
            acc2[i][2] += a.x*b0.z + a.y*b1v.z + a.z*b2v.z + a.w*b3v.z;
            acc2[i][3] += a.x*b0.w + a.y*b1v.w + a.z*b2v.w + a.w*b3v.w;
        }
    }
    float4 bb2 = *(const float4*)&b2[c];
    float4 w3v = *(const float4*)&w3s[c];
    float qp[4];
    #pragma unroll
    for (int i = 0; i < 4; i++){
        float vx = gelu_f(acc2[i][0] + bb2.x);
        float vy = gelu_f(acc2[i][1] + bb2.y);
        float vz = gelu_f(acc2[i][2] + bb2.z);
        float vw = gelu_f(acc2[i][3] + bb2.w);
        qp[i] = vx*w3v.x + vy*w3v.y + vz*w3v.z + vw*w3v.w;
    }
    // reduce over the 16 tc-threads of each row (consecutive lanes)
    #pragma unroll
    for (int off = 1; off < 16; off <<= 1){
        #pragma unroll
        for (int i = 0; i < 4; i++) qp[i] += __shfl_xor(qp[i], off);
    }
    if (tc == 0){
        float b3v = b3[0];
        #pragma unroll
        for (int i = 0; i < 4; i++){
            int q = r + i;
            if (q < n) atomicMin(&smin[batch[q]], enc_f(qp[i] + b3v));
        }
    }
    __syncthreads();
    if (t < 64 && smin[t] != 0xFFFFFFFFu) atomicMin(&qenc[t], smin[t]);
}

__global__ void k_qout(const unsigned int* __restrict__ qenc, float* __restrict__ out){
    int g = threadIdx.x;
    unsigned u = qenc[g];
    u = (u & 0x80000000u) ? (u & 0x7FFFFFFFu) : ~u;   // decode
    out[g] = __uint_as_float(u);
}

extern "C" void kernel_launch(void* const* d_in, const int* in_sizes, int n_in,
                              void* d_out, int out_size, void* d_ws, size_t ws_size,
                              hipStream_t stream){
    const float* x     = (const float*)d_in[0];
    const int*   ei    = (const int*)  d_in[1];
    const float* ea    = (const float*)d_in[2];
    const int*   batch = (const int*)  d_in[3];
    const float* linW  = (const float*)d_in[4];
    const float* linb  = (const float*)d_in[5];
    const float* convW = (const float*)d_in[6];
    const float* attS  = (const float*)d_in[7];
    const float* attD  = (const float*)d_in[8];
    const float* We    = (const float*)d_in[9];
    const float* attE  = (const float*)d_in[10];
    const float* convb = (const float*)d_in[11];
    const float* fc1W  = (const float*)d_in[12];
    const float* fc1b  = (const float*)d_in[13];
    const float* fc2W  = (const float*)d_in[14];
    const float* fc2b  = (const float*)d_in[15];
    const float* fc3W  = (const float*)d_in[16];
    const float* fc3b  = (const float*)d_in[17];

    int N = in_sizes[0] / 15;
    int E = in_sizes[1] / 2;

    char* w = (char*)d_ws;
    size_t o = 0;
    auto alloc = [&](size_t bytes) -> char* {
        char* p = w + o;
        o = (o + bytes + 255) & ~(size_t)255;
        return p;
    };
    double*   dsum   = (double*)  alloc(4 * 8);
    double*   Mm     = (double*)  alloc(2 * 12 * 8);
    double*   ael    = (double*)  alloc(2 * 4 * 8);
    float*    Wsrc   = (float*)   alloc(2 * 64 * 4 * 4);
    float*    Wdst   = (float*)   alloc(2 * 64 * 4 * 4);
    float*    Wt     = (float*)   alloc(2 * 256 * 64 * 4);
    unsigned* qenc   = (unsigned*)alloc(64 * 4);
    int*      deg    = (int*)     alloc((size_t)N * 4);
    int*      cursor = (int*)     alloc((size_t)N * 4);
    int*      rowptr = (int*)     alloc((size_t)(N + 1) * 4);
    int*      csum   = (int*)     alloc(64 * 4);
    int*      coff   = (int*)     alloc(64 * 4);
    int*      colsrc = (int*)     alloc((size_t)E * 4);
    float2*   e01    = (float2*)  alloc((size_t)E * 8);
    double*   e2md   = (double*)  alloc((size_t)E * 8);
    float*    asrc   = (float*)   alloc((size_t)N * 16);
    float*    adst   = (float*)   alloc((size_t)N * 16);
    float*    hA     = (float*)   alloc((size_t)N * 256);
    float*    hB     = (float*)   alloc((size_t)N * 256);
    float*    agg    = (float*)   alloc((size_t)N * 1024);
    (void)ws_size; (void)n_in; (void)out_size;

    hipMemsetAsync(dsum, 0, 4 * 8, stream);
    hipMemsetAsync(deg, 0, (size_t)N * 4, stream);
    hipMemsetAsync(qenc, 0xFF, 64 * 4, stream);

    int nchunk = (N + 1023) / 1024;

    k_edge_stats<<<1024, 256, 0, stream>>>(ei, ea, E, dsum, deg);
    k_params<<<1, 256, 0, stream>>>(dsum, E, convW, attS, attD, We, attE, Mm, ael, Wsrc, Wdst, Wt);
    k_chunk_sum<<<nchunk, 256, 0, stream>>>(deg, N, csum);
    k_chunk_scan<<<1, 64, 0, stream>>>(csum, nchunk, coff, rowptr + N);
    k_row_ptr<<<nchunk, 1024, 0, stream>>>(deg, N, coff, rowptr, cursor);
    k_scatter<<<1024, 256, 0, stream>>>(ei, ea, E, cursor, colsrc, e01, e2md);

    k_lin_in<<<(N + 3) / 4, 256, 0, stream>>>(x, linW, linb, hA, N);

    int gN = (N + 255) / 256, gW = (N + 3) / 4, gR = (N + 63) / 64;

    // layer 0 (no residual)
    k_attcoef<<<gN, 256, 0, stream>>>(hA, Wsrc, Wdst, asrc, adst, N);
    k_gat<<<gW, 256, 0, stream>>>(hA, asrc, adst, rowptr, colsrc, e01, e2md, Mm, ael, agg, N);
    k_gemm<256, false, true><<<gR, 256, 0, stream>>>(agg, Wt, convb, nullptr, hB, N);

    // layer 1 (residual)
    k_attcoef<<<gN, 256, 0, stream>>>(hB, Wsrc + 256, Wdst + 256, asrc, adst, N);
    k_gat<<<gW, 256, 0, stream>>>(hB, asrc, adst, rowptr, colsrc, e01, e2md, Mm + 12, ael + 4, agg, N);
    k_gemm<256, true, true><<<gR, 256, 0, stream>>>(agg, Wt + 16384, convb + 64, hB, hA, N);

    // fused FC head + per-graph min
    k_fc<<<gR, 256, 0, stream>>>(hA, fc1W, fc1b, fc2W, fc2b, fc3W, fc3b, batch, qenc, N);
    k_qout<<<1, 64, 0, stream>>>(qenc, (float*)d_out);
}